// Round 11
// baseline (52.339 us; speedup 1.0000x reference)
//
#include <hip/hip_runtime.h>
#include <hip/hip_bf16.h>

typedef _Float16 f16x8 __attribute__((ext_vector_type(8)));
typedef _Float16 f16x2 __attribute__((ext_vector_type(2)));
typedef float f32x4  __attribute__((ext_vector_type(4)));

#define Bn 4
#define Cn 64
#define Hn 128
#define Wn 128
#define HWn 16384

// ws layout (bytes):
//   xt     [B][H][seg0..7][W][8ch] f16 @ 0   (8 MB)
//   pk_def [18][4][64][8] f16 @ XT_BYTES     B-frags, main conv
//   pk_off [18][3][64][8] f16 @ +PKDEF       B-frags, offset conv
#define XT_BYTES    (Bn*HWn*Cn*2)
#define PKDEF_BYTES (18*4*64*8*2)

static __device__ __forceinline__ unsigned pk_f16(float lo, float hi) {
  union { _Float16 h[2]; unsigned u; } cv;
  cv.h[0] = (_Float16)lo; cv.h[1] = (_Float16)hi;
  return cv.u;
}

// ---- merged: blocks 0..1023 transpose x -> xt; blocks 1024..1055 pack weights.
__global__ __launch_bounds__(256) void prep_all(const float* __restrict__ x,
                                                const float* __restrict__ w_off,
                                                const float* __restrict__ w_def,
                                                ushort* __restrict__ xt,
                                                ushort* __restrict__ pk_def,
                                                ushort* __restrict__ pk_off) {
  __shared__ float tile[64][68];         // stride 68 f32 = 272B: 16B-aligned rows
  const int t = threadIdx.x;
  const int blk = blockIdx.x;
  if (blk < 1024) {                      // ---- transpose_cast
    const int b = blk >> 8;
    const int pix0 = (blk & 255) * 64;
    const int y = pix0 >> 7, x0 = pix0 & 127;
    const float* xb = x + (b * Cn) * HWn + pix0;
#pragma unroll
    for (int q = 0; q < 4; ++q) {        // float4 loads: 16B/lane
      int idx = q * 256 + t;             // 1024 slots = 64 rows x 16 float4
      int c = idx >> 4, p4 = idx & 15;
      float4 v = *(const float4*)(xb + c * HWn + p4 * 4);
      *(float4*)&tile[c][p4 * 4] = v;
    }
    __syncthreads();
    const int p = t & 63, cg = t >> 6;
#pragma unroll
    for (int half = 0; half < 2; ++half) {
      const int seg = cg * 2 + half;
      unsigned u[4];
#pragma unroll
      for (int j = 0; j < 4; ++j)
        u[j] = pk_f16(tile[seg * 8 + 2 * j][p], tile[seg * 8 + 2 * j + 1][p]);
      uint4 v = {u[0], u[1], u[2], u[3]};
      *(uint4*)(xt + (((((b << 7) + y) << 3) + seg) * 128 + x0 + p) * 8) = v;
    }
  } else {                               // ---- prep_pack
    const int tt = (blk - 1024) * 256 + t;
    if (tt < 4608) {                     // 18*4*64
      int lane = tt & 63, oc = (tt >> 6) & 3, s = tt >> 8;
      int g = s / 9, k = s % 9;
      int o = oc * 16 + (lane & 15);
      int cb = g * 32 + (lane >> 4) * 8;
      unsigned u[4];
#pragma unroll
      for (int j = 0; j < 4; ++j)
        u[j] = pk_f16(w_def[(o * Cn + cb + 2 * j) * 9 + k],
                      w_def[(o * Cn + cb + 2 * j + 1) * 9 + k]);
      uint4 v = {u[0], u[1], u[2], u[3]};
      *(uint4*)(pk_def + tt * 8) = v;
    } else if (tt < 8064) {              // + 18*3*64
      int t2 = tt - 4608;
      int lane = t2 & 63, r = t2 >> 6;   // r = s*3 + oc
      int oc = r % 3, s = r / 3;
      int k = s >> 1, chalf = s & 1;
      int o = oc * 16 + (lane & 15);
      int cb = chalf * 32 + (lane >> 4) * 8;
      unsigned u[4];
#pragma unroll
      for (int j = 0; j < 4; ++j) {
        float lo = (o < 36) ? w_off[(o * Cn + cb + 2 * j) * 9 + k] : 0.f;
        float hi = (o < 36) ? w_off[(o * Cn + cb + 2 * j + 1) * 9 + k] : 0.f;
        u[j] = pk_f16(lo, hi);
      }
      uint4 v = {u[0], u[1], u[2], u[3]};
      *(uint4*)(pk_off + (r * 64 + lane) * 8) = v;
    }
  }
}

// ---- FUSED: 16x8 pixel tile, 1024 thr = 16 waves = 8 pixel-rows x 2 gsel.
// Grid 512 = exactly 2 blocks/CU resident. LDS 62,848 B.
// T_STRIDE padded +16 ushorts: plane spacing 6560B, 6560%128=32 -> the 4 kq
// planes of a wave hit disjoint bank quadrants (kills the 4-way conflict).
#define T_STRIDE (17*24*8 + 16)
__global__ __launch_bounds__(1024, 8) void deform_fused(const ushort* __restrict__ xt,
                                                        const ushort* __restrict__ pk_def,
                                                        const ushort* __restrict__ pk_off,
                                                        float* __restrict__ out) {
  __shared__ ushort tile[8 * T_STRIDE];      // 52,480 B (reduce buf aliases later)
  __shared__ _Float16 off_lds[8][36][18];    // 10,368 B
  const int t = threadIdx.x;
  const int lane = t & 63;
  const int wid = t >> 6;                // 0..15
  const int pg = wid >> 1, gsel = wid & 1;
  int bid = blockIdx.x;
  bid = (bid & 7) * 64 + (bid >> 3);     // bijective XCD swizzle (512 % 8 == 0)
  const int b  = bid >> 7;
  const int ty = (bid >> 3) & 15;
  const int tx = bid & 7;
  const int y0t = ty * 8, x0t = tx * 16;
  const int TLY = max(0, y0t - 4), THY = min(127, y0t + 12);
  const int TLX = max(0, x0t - 3), THX = min(127, x0t + 19);
  const int Hd = THY - TLY + 1, Wd = THX - TLX + 1;

  { // stage [8 seg][Hd][Wd][8ch] -> LDS (coalesced 16B/lane)
    const int xq = t & 31;
    const int r0 = t >> 5;               // 32 row-groups
    const int nr = Hd * 8;
    for (int rr = r0; rr < nr; rr += 32) {
      const int yq = rr >> 3, seg = rr & 7;
      if (xq < Wd) {
        const ushort* src = xt + ((((b << 7) + TLY + yq) << 3) + seg) * 1024 + (TLX + xq) * 8;
        *(uint4*)&tile[seg * T_STRIDE + (yq * 24 + xq) * 8] = *(const uint4*)src;
      }
    }
  }
  __syncthreads();

  const int h = y0t + pg;
  const int p = lane & 15, kq = lane >> 4;
  const int w_ = x0t + p;
  const int pixin = (h << 7) + x0t;
  const int su = gsel * 4 + kq;
  const int colb = lane & 15;

  // hoisted per-tap data for the regular 3x3 (shared by ph1's two ch-halves)
  int pixoff[9]; bool tvalid[9];
#pragma unroll
  for (int kk = 0; kk < 9; ++kk) {
    int yk = h + kk / 3 - 1, xk = w_ + kk % 3 - 1;
    tvalid[kk] = ((unsigned)yk < 128u) && ((unsigned)xk < 128u);
    int yc = min(max(yk, 0), 127), xc = min(max(xk, 0), 127);
    pixoff[kk] = ((yc - TLY) * 24 + (xc - TLX)) * 8;
  }

  // ---- phase 1: offset conv from staged tile.
  // N-split: gsel0 -> off ch 0-15; gsel1 -> 16-31 & 32-35.
  {
    f32x4 oa0 = {0,0,0,0}, oa1 = {0,0,0,0}, oa2 = {0,0,0,0};
    const f16x8* pBo = (const f16x8*)pk_off;
#pragma unroll
    for (int s = 0; s < 18; ++s) {
      const int k = s >> 1, chalf = s & 1;
      uint4 t_ = *(const uint4*)&tile[(chalf * 4 + kq) * T_STRIDE + pixoff[k]];
      if (!tvalid[k]) { t_.x = 0; t_.y = 0; t_.z = 0; t_.w = 0; }
      union { uint4 u; f16x8 v; } A; A.u = t_;
      if (gsel == 0) {
        oa0 = __builtin_amdgcn_mfma_f32_16x16x32_f16(A.v, pBo[(s*3 + 0)*64 + lane], oa0, 0,0,0);
      } else {
        oa1 = __builtin_amdgcn_mfma_f32_16x16x32_f16(A.v, pBo[(s*3 + 1)*64 + lane], oa1, 0,0,0);
        oa2 = __builtin_amdgcn_mfma_f32_16x16x32_f16(A.v, pBo[(s*3 + 2)*64 + lane], oa2, 0,0,0);
      }
    }
    // D: col = lane&15 = offset channel (within 16-group), row = kq*4+r = pixel x
    if (gsel == 0) {
#pragma unroll
      for (int r = 0; r < 4; ++r) off_lds[pg][colb][kq * 4 + r] = (_Float16)oa0[r];
    } else {
#pragma unroll
      for (int r = 0; r < 4; ++r) {
        off_lds[pg][16 + colb][kq * 4 + r] = (_Float16)oa1[r];
        if (colb < 4) off_lds[pg][32 + colb][kq * 4 + r] = (_Float16)oa2[r];
      }
    }
  }
  __syncthreads();

  // this wave's 18 offset channels for its pixel (broadcast across kq)
  float offv[18];
#pragma unroll
  for (int j = 0; j < 18; ++j) offv[j] = (float)off_lds[pg][gsel * 18 + j][p];

  // ---- phase 2: deformable gather + packed-f16 bilinear + main MFMA
  f32x4 acc0={0,0,0,0}, acc1={0,0,0,0}, acc2={0,0,0,0}, acc3={0,0,0,0};
  const f16x8* pB = (const f16x8*)pk_def;

#pragma unroll
  for (int j = 0; j < 9; ++j) {
    const int k = j;
    float py = offv[2*j]   + (float)(h  + k / 3 - 1);
    float px = offv[2*j+1] + (float)(w_ + k % 3 - 1);
    float fy = floorf(py), fx = floorf(px);
    int y0 = (int)fy, x0 = (int)fx;
    float dy = py - fy, dx = px - fx;

    bool vy0 = (y0 >= 0) && (y0 < Hn);
    bool vy1 = (y0 >= -1) && (y0 < Hn - 1);
    bool vx0 = (x0 >= 0) && (x0 < Wn);
    bool vx1 = (x0 >= -1) && (x0 < Wn - 1);
    float omdy = 1.f - dy, omdx = 1.f - dx;
    float w00 = (vy0 && vx0) ? omdy * omdx : 0.f;
    float w01 = (vy0 && vx1) ? omdy * dx   : 0.f;
    float w10 = (vy1 && vx0) ? dy * omdx   : 0.f;
    float w11 = (vy1 && vx1) ? dy * dx     : 0.f;

    int iy0 = min(max(y0, 0), Hn - 1), iy1 = min(max(y0 + 1, 0), Hn - 1);
    int ix0 = min(max(x0, 0), Wn - 1), ix1 = min(max(x0 + 1, 0), Wn - 1);

    uint4 c00, c01, c10, c11;
    bool intile = (iy0 >= TLY) && (iy1 <= THY) && (ix0 >= TLX) && (ix1 <= THX);
    if (__all((int)intile)) {            // fast path: LDS
      const int base = su * T_STRIDE;
      const int ly0 = iy0 - TLY, ly1 = iy1 - TLY;
      const int lx0 = ix0 - TLX, lx1 = ix1 - TLX;
      c00 = *(const uint4*)&tile[base + (ly0 * 24 + lx0) * 8];
      c01 = *(const uint4*)&tile[base + (ly0 * 24 + lx1) * 8];
      c10 = *(const uint4*)&tile[base + (ly1 * 24 + lx0) * 8];
      c11 = *(const uint4*)&tile[base + (ly1 * 24 + lx1) * 8];
    } else {                             // rare fallback: global gather (L2-hot)
      const int r0g = ((((b << 7) + iy0) << 3) + su) * 128;
      const int r1g = ((((b << 7) + iy1) << 3) + su) * 128;
      c00 = *(const uint4*)(xt + (r0g + ix0) * 8);
      c01 = *(const uint4*)(xt + (r0g + ix1) * 8);
      c10 = *(const uint4*)(xt + (r1g + ix0) * 8);
      c11 = *(const uint4*)(xt + (r1g + ix1) * 8);
    }

    // packed-f16 bilinear: result words ARE the f16 MFMA A-fragment
    const _Float16 h00 = (_Float16)w00, h01 = (_Float16)w01;
    const _Float16 h10 = (_Float16)w10, h11 = (_Float16)w11;
    const f16x2 W00 = {h00, h00}, W01 = {h01, h01};
    const f16x2 W10 = {h10, h10}, W11 = {h11, h11};
    union U32H { unsigned u; f16x2 h; };
    union { uint4 u; f16x8 v; } A;
#define BILC(comp, fld)                                                        \
    { U32H a0, a1, a2, a3, r;                                                  \
      a0.u = c00.comp; a1.u = c01.comp; a2.u = c10.comp; a3.u = c11.comp;      \
      r.h = a0.h * W00 + a1.h * W01 + a2.h * W10 + a3.h * W11;                 \
      A.u.fld = r.u; }
    BILC(x, x) BILC(y, y) BILC(z, z) BILC(w, w)
#undef BILC

    const int s = gsel * 9 + j;
    __builtin_amdgcn_s_setprio(1);
    acc0 = __builtin_amdgcn_mfma_f32_16x16x32_f16(A.v, pB[(s*4 + 0)*64 + lane], acc0, 0,0,0);
    acc1 = __builtin_amdgcn_mfma_f32_16x16x32_f16(A.v, pB[(s*4 + 1)*64 + lane], acc1, 0,0,0);
    acc2 = __builtin_amdgcn_mfma_f32_16x16x32_f16(A.v, pB[(s*4 + 2)*64 + lane], acc2, 0,0,0);
    acc3 = __builtin_amdgcn_mfma_f32_16x16x32_f16(A.v, pB[(s*4 + 3)*64 + lane], acc3, 0,0,0);
    __builtin_amdgcn_s_setprio(0);
  }

  __syncthreads();                       // all waves done with tile
  // symmetric pair-reduce: gsel1 contributes acc0/1, gsel0 contributes acc2/3;
  // each wave then finishes and writes 32 of the 64 output channels.
  float* red = (float*)tile;             // [8][4][64][4] f32 = 32 KB (aliases tile)
  if (gsel == 1) {
    *(f32x4*)&red[((pg * 4 + 0) * 64 + lane) * 4] = acc0;
    *(f32x4*)&red[((pg * 4 + 1) * 64 + lane) * 4] = acc1;
  } else {
    *(f32x4*)&red[((pg * 4 + 2) * 64 + lane) * 4] = acc2;
    *(f32x4*)&red[((pg * 4 + 3) * 64 + lane) * 4] = acc3;
  }
  __syncthreads();
  float* ob = out + pixin + kq * 4;
  if (gsel == 0) {
    acc0 += *(const f32x4*)&red[((pg * 4 + 0) * 64 + lane) * 4];
    acc1 += *(const f32x4*)&red[((pg * 4 + 1) * 64 + lane) * 4];
#pragma unroll
    for (int r = 0; r < 4; ++r) {
      ob[((b*64 +      colb) << 14) + r] = acc0[r];
      ob[((b*64 + 16 + colb) << 14) + r] = acc1[r];
    }
  } else {
    acc2 += *(const f32x4*)&red[((pg * 4 + 2) * 64 + lane) * 4];
    acc3 += *(const f32x4*)&red[((pg * 4 + 3) * 64 + lane) * 4];
#pragma unroll
    for (int r = 0; r < 4; ++r) {
      ob[((b*64 + 32 + colb) << 14) + r] = acc2[r];
      ob[((b*64 + 48 + colb) << 14) + r] = acc3[r];
    }
  }
}

extern "C" void kernel_launch(void* const* d_in, const int* in_sizes, int n_in,
                              void* d_out, int out_size, void* d_ws, size_t ws_size,
                              hipStream_t stream) {
  const float* x     = (const float*)d_in[0];
  const float* w_off = (const float*)d_in[1];
  const float* w_def = (const float*)d_in[2];
  float* out = (float*)d_out;

  char* ws = (char*)d_ws;
  ushort* xt     = (ushort*)ws;
  ushort* pk_def = (ushort*)(ws + XT_BYTES);
  ushort* pk_off = (ushort*)(ws + XT_BYTES + PKDEF_BYTES);

  prep_all<<<1056, 256, 0, stream>>>(x, w_off, w_def, xt, pk_def, pk_off);
  deform_fused<<<512, 1024, 0, stream>>>(xt, pk_def, pk_off, out);
}

// Round 12
// 51.193 us; speedup vs baseline: 1.0224x; 1.0224x over previous
//
#include <hip/hip_runtime.h>
#include <hip/hip_bf16.h>

typedef _Float16 f16x8 __attribute__((ext_vector_type(8)));
typedef _Float16 f16x2 __attribute__((ext_vector_type(2)));
typedef float f32x4  __attribute__((ext_vector_type(4)));

#define Bn 4
#define Cn 64
#define Hn 128
#define Wn 128
#define HWn 16384

// ws layout (bytes):
//   xt     [B][H][seg0..7][W][8ch] f16 @ 0   (8 MB)
//   pk_def [18][4][64][8] f16 @ XT_BYTES     B-frags, main conv
//   pk_off [18][3][64][8] f16 @ +PKDEF       B-frags, offset conv
#define XT_BYTES    (Bn*HWn*Cn*2)
#define PKDEF_BYTES (18*4*64*8*2)

static __device__ __forceinline__ unsigned pk_f16(float lo, float hi) {
  union { _Float16 h[2]; unsigned u; } cv;
  cv.h[0] = (_Float16)lo; cv.h[1] = (_Float16)hi;
  return cv.u;
}

// ---- merged: blocks 0..1023 transpose x -> xt; blocks 1024..1055 pack weights.
__global__ __launch_bounds__(256) void prep_all(const float* __restrict__ x,
                                                const float* __restrict__ w_off,
                                                const float* __restrict__ w_def,
                                                ushort* __restrict__ xt,
                                                ushort* __restrict__ pk_def,
                                                ushort* __restrict__ pk_off) {
  __shared__ float tile[64][68];
  const int t = threadIdx.x;
  const int blk = blockIdx.x;
  if (blk < 1024) {                      // ---- transpose_cast
    const int b = blk >> 8;
    const int pix0 = (blk & 255) * 64;
    const int y = pix0 >> 7, x0 = pix0 & 127;
    const float* xb = x + (b * Cn) * HWn + pix0;
#pragma unroll
    for (int q = 0; q < 4; ++q) {        // float4 loads: 16B/lane
      int idx = q * 256 + t;
      int c = idx >> 4, p4 = idx & 15;
      float4 v = *(const float4*)(xb + c * HWn + p4 * 4);
      *(float4*)&tile[c][p4 * 4] = v;
    }
    __syncthreads();
    const int p = t & 63, cg = t >> 6;
#pragma unroll
    for (int half = 0; half < 2; ++half) {
      const int seg = cg * 2 + half;
      unsigned u[4];
#pragma unroll
      for (int j = 0; j < 4; ++j)
        u[j] = pk_f16(tile[seg * 8 + 2 * j][p], tile[seg * 8 + 2 * j + 1][p]);
      uint4 v = {u[0], u[1], u[2], u[3]};
      *(uint4*)(xt + (((((b << 7) + y) << 3) + seg) * 128 + x0 + p) * 8) = v;
    }
  } else {                               // ---- prep_pack
    const int tt = (blk - 1024) * 256 + t;
    if (tt < 4608) {                     // 18*4*64
      int lane = tt & 63, oc = (tt >> 6) & 3, s = tt >> 8;
      int g = s / 9, k = s % 9;
      int o = oc * 16 + (lane & 15);
      int cb = g * 32 + (lane >> 4) * 8;
      unsigned u[4];
#pragma unroll
      for (int j = 0; j < 4; ++j)
        u[j] = pk_f16(w_def[(o * Cn + cb + 2 * j) * 9 + k],
                      w_def[(o * Cn + cb + 2 * j + 1) * 9 + k]);
      uint4 v = {u[0], u[1], u[2], u[3]};
      *(uint4*)(pk_def + tt * 8) = v;
    } else if (tt < 8064) {              // + 18*3*64
      int t2 = tt - 4608;
      int lane = t2 & 63, r = t2 >> 6;   // r = s*3 + oc
      int oc = r % 3, s = r / 3;
      int k = s >> 1, chalf = s & 1;
      int o = oc * 16 + (lane & 15);
      int cb = chalf * 32 + (lane >> 4) * 8;
      unsigned u[4];
#pragma unroll
      for (int j = 0; j < 4; ++j) {
        float lo = (o < 36) ? w_off[(o * Cn + cb + 2 * j) * 9 + k] : 0.f;
        float hi = (o < 36) ? w_off[(o * Cn + cb + 2 * j + 1) * 9 + k] : 0.f;
        u[j] = pk_f16(lo, hi);
      }
      uint4 v = {u[0], u[1], u[2], u[3]};
      *(uint4*)(pk_off + (r * 64 + lane) * 8) = v;
    }
  }
}

// ---- FUSED: 16x8 pixel tile, 1024 thr = 16 waves = 8 pixel-rows x 2 gsel.
// launch_bounds(1024,4): VGPR cap 128 -> room for explicit depth-2 pipeline.
// 1 block/CU resident; grid 512 = exactly 2 full rounds. LDS 62,848 B.
#define T_STRIDE (17*24*8 + 16)
__global__ __launch_bounds__(1024, 4) void deform_fused(const ushort* __restrict__ xt,
                                                        const ushort* __restrict__ pk_def,
                                                        const ushort* __restrict__ pk_off,
                                                        float* __restrict__ out) {
  __shared__ ushort tile[8 * T_STRIDE];      // 52,480 B (reduce buf aliases later)
  __shared__ _Float16 off_lds[8][36][18];    // 10,368 B
  const int t = threadIdx.x;
  const int lane = t & 63;
  const int wid = t >> 6;                // 0..15
  const int pg = wid >> 1, gsel = wid & 1;
  int bid = blockIdx.x;
  bid = (bid & 7) * 64 + (bid >> 3);     // bijective XCD swizzle (512 % 8 == 0)
  const int b  = bid >> 7;
  const int ty = (bid >> 3) & 15;
  const int tx = bid & 7;
  const int y0t = ty * 8, x0t = tx * 16;
  const int TLY = max(0, y0t - 4), THY = min(127, y0t + 12);
  const int TLX = max(0, x0t - 3), THX = min(127, x0t + 19);
  const int Hd = THY - TLY + 1, Wd = THX - TLX + 1;

  { // stage [8 seg][Hd][Wd][8ch] -> LDS (coalesced 16B/lane)
    const int xq = t & 31;
    const int r0 = t >> 5;               // 32 row-groups
    const int nr = Hd * 8;
    for (int rr = r0; rr < nr; rr += 32) {
      const int yq = rr >> 3, seg = rr & 7;
      if (xq < Wd) {
        const ushort* src = xt + ((((b << 7) + TLY + yq) << 3) + seg) * 1024 + (TLX + xq) * 8;
        *(uint4*)&tile[seg * T_STRIDE + (yq * 24 + xq) * 8] = *(const uint4*)src;
      }
    }
  }
  __syncthreads();

  const int h = y0t + pg;
  const int p = lane & 15, kq = lane >> 4;
  const int w_ = x0t + p;
  const int pixin = (h << 7) + x0t;
  const int su = gsel * 4 + kq;
  const int colb = lane & 15;

  // hoisted per-tap data for the regular 3x3 (shared by ph1's two ch-halves)
  int pixoff[9]; bool tvalid[9];
#pragma unroll
  for (int kk = 0; kk < 9; ++kk) {
    int yk = h + kk / 3 - 1, xk = w_ + kk % 3 - 1;
    tvalid[kk] = ((unsigned)yk < 128u) && ((unsigned)xk < 128u);
    int yc = min(max(yk, 0), 127), xc = min(max(xk, 0), 127);
    pixoff[kk] = ((yc - TLY) * 24 + (xc - TLX)) * 8;
  }

  // ---- phase 1: offset conv from staged tile, depth-2 A prefetch.
  // N-split: gsel0 -> off ch 0-15; gsel1 -> 16-31 & 32-35.
  {
    f32x4 oa0 = {0,0,0,0}, oa1 = {0,0,0,0}, oa2 = {0,0,0,0};
    const f16x8* pBo = (const f16x8*)pk_off;
    uint4 av[2];
#define OLOADA(s_, dst) {                                                      \
    const int k_ = (s_) >> 1, ch_ = (s_) & 1;                                  \
    uint4 t_ = *(const uint4*)&tile[(ch_ * 4 + kq) * T_STRIDE + pixoff[k_]];   \
    if (!tvalid[k_]) { t_.x = 0; t_.y = 0; t_.z = 0; t_.w = 0; }               \
    dst = t_; }
    OLOADA(0, av[0])
#pragma unroll
    for (int s = 0; s < 18; ++s) {
      if (s + 1 < 18) OLOADA(s + 1, av[(s + 1) & 1])
      union { uint4 u; f16x8 v; } A; A.u = av[s & 1];
      if (gsel == 0) {
        oa0 = __builtin_amdgcn_mfma_f32_16x16x32_f16(A.v, pBo[(s*3 + 0)*64 + lane], oa0, 0,0,0);
      } else {
        oa1 = __builtin_amdgcn_mfma_f32_16x16x32_f16(A.v, pBo[(s*3 + 1)*64 + lane], oa1, 0,0,0);
        oa2 = __builtin_amdgcn_mfma_f32_16x16x32_f16(A.v, pBo[(s*3 + 2)*64 + lane], oa2, 0,0,0);
      }
    }
#undef OLOADA
    if (gsel == 0) {
#pragma unroll
      for (int r = 0; r < 4; ++r) off_lds[pg][colb][kq * 4 + r] = (_Float16)oa0[r];
    } else {
#pragma unroll
      for (int r = 0; r < 4; ++r) {
        off_lds[pg][16 + colb][kq * 4 + r] = (_Float16)oa1[r];
        if (colb < 4) off_lds[pg][32 + colb][kq * 4 + r] = (_Float16)oa2[r];
      }
    }
  }
  __syncthreads();

  // this wave's 18 offset channels for its pixel (broadcast across kq)
  float offv[18];
#pragma unroll
  for (int j = 0; j < 18; ++j) offv[j] = (float)off_lds[pg][gsel * 18 + j][p];

  // ---- phase 2: depth-2 pipelined deformable gather + f16 bilinear + MFMA
  f32x4 acc0={0,0,0,0}, acc1={0,0,0,0}, acc2={0,0,0,0}, acc3={0,0,0,0};
  const f16x8* pB = (const f16x8*)pk_def;

  struct Stage { f16x2 W00, W01, W10, W11; uint4 c00, c01, c10, c11; };
  Stage st[2];

#define DPREP(j_, S) {                                                         \
    const int k_ = (j_);                                                       \
    float py = offv[2*(j_)]   + (float)(h  + k_ / 3 - 1);                      \
    float px = offv[2*(j_)+1] + (float)(w_ + k_ % 3 - 1);                      \
    float fy = floorf(py), fx = floorf(px);                                    \
    int y0 = (int)fy, x0 = (int)fx;                                            \
    float dy = py - fy, dx = px - fx;                                          \
    bool vy0 = (y0 >= 0) && (y0 < Hn);                                         \
    bool vy1 = (y0 >= -1) && (y0 < Hn - 1);                                    \
    bool vx0 = (x0 >= 0) && (x0 < Wn);                                         \
    bool vx1 = (x0 >= -1) && (x0 < Wn - 1);                                    \
    float omdy = 1.f - dy, omdx = 1.f - dx;                                    \
    float w00 = (vy0 && vx0) ? omdy * omdx : 0.f;                              \
    float w01 = (vy0 && vx1) ? omdy * dx   : 0.f;                              \
    float w10 = (vy1 && vx0) ? dy * omdx   : 0.f;                              \
    float w11 = (vy1 && vx1) ? dy * dx     : 0.f;                              \
    { _Float16 hh_;                                                            \
      hh_ = (_Float16)w00; S.W00[0] = hh_; S.W00[1] = hh_;                     \
      hh_ = (_Float16)w01; S.W01[0] = hh_; S.W01[1] = hh_;                     \
      hh_ = (_Float16)w10; S.W10[0] = hh_; S.W10[1] = hh_;                     \
      hh_ = (_Float16)w11; S.W11[0] = hh_; S.W11[1] = hh_; }                   \
    int iy0 = min(max(y0, 0), Hn - 1), iy1 = min(max(y0 + 1, 0), Hn - 1);      \
    int ix0 = min(max(x0, 0), Wn - 1), ix1 = min(max(x0 + 1, 0), Wn - 1);      \
    bool intile = (iy0 >= TLY) && (iy1 <= THY) && (ix0 >= TLX) && (ix1 <= THX);\
    if (__all((int)intile)) {                                                  \
      const int base = su * T_STRIDE;                                          \
      const int ly0 = iy0 - TLY, ly1 = iy1 - TLY;                              \
      const int lx0 = ix0 - TLX, lx1 = ix1 - TLX;                              \
      S.c00 = *(const uint4*)&tile[base + (ly0 * 24 + lx0) * 8];               \
      S.c01 = *(const uint4*)&tile[base + (ly0 * 24 + lx1) * 8];               \
      S.c10 = *(const uint4*)&tile[base + (ly1 * 24 + lx0) * 8];               \
      S.c11 = *(const uint4*)&tile[base + (ly1 * 24 + lx1) * 8];               \
    } else {                                                                   \
      const int r0g = ((((b << 7) + iy0) << 3) + su) * 128;                    \
      const int r1g = ((((b << 7) + iy1) << 3) + su) * 128;                    \
      S.c00 = *(const uint4*)(xt + (r0g + ix0) * 8);                           \
      S.c01 = *(const uint4*)(xt + (r0g + ix1) * 8);                           \
      S.c10 = *(const uint4*)(xt + (r1g + ix0) * 8);                           \
      S.c11 = *(const uint4*)(xt + (r1g + ix1) * 8);                           \
    } }

  DPREP(0, st[0])
#pragma unroll
  for (int j = 0; j < 9; ++j) {
    if (j + 1 < 9) DPREP(j + 1, st[(j + 1) & 1])
    Stage& S = st[j & 1];
    union U32H { unsigned u; f16x2 h; };
    union { uint4 u; f16x8 v; } A;
#define BILC(comp, fld)                                                        \
    { U32H a0, a1, a2, a3, r;                                                  \
      a0.u = S.c00.comp; a1.u = S.c01.comp; a2.u = S.c10.comp; a3.u = S.c11.comp; \
      r.h = a0.h * S.W00 + a1.h * S.W01 + a2.h * S.W10 + a3.h * S.W11;         \
      A.u.fld = r.u; }
    BILC(x, x) BILC(y, y) BILC(z, z) BILC(w, w)
#undef BILC

    const int s = gsel * 9 + j;
    __builtin_amdgcn_s_setprio(1);
    acc0 = __builtin_amdgcn_mfma_f32_16x16x32_f16(A.v, pB[(s*4 + 0)*64 + lane], acc0, 0,0,0);
    acc1 = __builtin_amdgcn_mfma_f32_16x16x32_f16(A.v, pB[(s*4 + 1)*64 + lane], acc1, 0,0,0);
    acc2 = __builtin_amdgcn_mfma_f32_16x16x32_f16(A.v, pB[(s*4 + 2)*64 + lane], acc2, 0,0,0);
    acc3 = __builtin_amdgcn_mfma_f32_16x16x32_f16(A.v, pB[(s*4 + 3)*64 + lane], acc3, 0,0,0);
    __builtin_amdgcn_s_setprio(0);
  }
#undef DPREP

  __syncthreads();                       // all waves done with tile
  // symmetric pair-reduce: gsel1 contributes acc0/1, gsel0 contributes acc2/3;
  // each wave then finishes and writes 32 of the 64 output channels.
  float* red = (float*)tile;             // [8][4][64][4] f32 = 32 KB (aliases tile)
  if (gsel == 1) {
    *(f32x4*)&red[((pg * 4 + 0) * 64 + lane) * 4] = acc0;
    *(f32x4*)&red[((pg * 4 + 1) * 64 + lane) * 4] = acc1;
  } else {
    *(f32x4*)&red[((pg * 4 + 2) * 64 + lane) * 4] = acc2;
    *(f32x4*)&red[((pg * 4 + 3) * 64 + lane) * 4] = acc3;
  }
  __syncthreads();
  float* ob = out + pixin + kq * 4;
  if (gsel == 0) {
    acc0 += *(const f32x4*)&red[((pg * 4 + 0) * 64 + lane) * 4];
    acc1 += *(const f32x4*)&red[((pg * 4 + 1) * 64 + lane) * 4];
#pragma unroll
    for (int r = 0; r < 4; ++r) {
      ob[((b*64 +      colb) << 14) + r] = acc0[r];
      ob[((b*64 + 16 + colb) << 14) + r] = acc1[r];
    }
  } else {
    acc2 += *(const f32x4*)&red[((pg * 4 + 2) * 64 + lane) * 4];
    acc3 += *(const f32x4*)&red[((pg * 4 + 3) * 64 + lane) * 4];
#pragma unroll
    for (int r = 0; r < 4; ++r) {
      ob[((b*64 + 32 + colb) << 14) + r] = acc2[r];
      ob[((b*64 + 48 + colb) << 14) + r] = acc3[r];
    }
  }
}

extern "C" void kernel_launch(void* const* d_in, const int* in_sizes, int n_in,
                              void* d_out, int out_size, void* d_ws, size_t ws_size,
                              hipStream_t stream) {
  const float* x     = (const float*)d_in[0];
  const float* w_off = (const float*)d_in[1];
  const float* w_def = (const float*)d_in[2];
  float* out = (float*)d_out;

  char* ws = (char*)d_ws;
  ushort* xt     = (ushort*)ws;
  ushort* pk_def = (ushort*)(ws + XT_BYTES);
  ushort* pk_off = (ushort*)(ws + XT_BYTES + PKDEF_BYTES);

  prep_all<<<1056, 256, 0, stream>>>(x, w_off, w_def, xt, pk_def, pk_off);
  deform_fused<<<512, 1024, 0, stream>>>(xt, pk_def, pk_off, out);
}